// Round 2
// 889.920 us; speedup vs baseline: 1.1207x; 1.1207x over previous
//
#include <hip/hip_runtime.h>
#include <stdint.h>

// Problem constants: B=2, S=2048, D=1024, H=16, DH=64
#define S_ 2048
#define NKT_ 32   // S_/64 key tiles
#define LP 72     // padded LDS row stride in shorts for the P tile only

typedef short bf16x8 __attribute__((ext_vector_type(8)));
typedef float f32x4 __attribute__((ext_vector_type(4)));

// fp32 -> bf16 round-to-nearest-even
__device__ __forceinline__ short f2bf(float x) {
  union { float f; uint32_t u; } v; v.f = x;
  uint32_t r = v.u + 0x7fffu + ((v.u >> 16) & 1u);
  return (short)(r >> 16);
}
// bf16 bits -> fp32
__device__ __forceinline__ float bf2f(short s) {
  union { uint32_t u; float f; } v; v.u = ((uint32_t)(uint16_t)s) << 16;
  return v.f;
}

// async global->LDS, 16B per lane. LDS dest is wave-uniform base + lane*16
// (hardware semantics); global src is per-lane.
__device__ __forceinline__ void gload16(const void* g, void* l) {
  __builtin_amdgcn_global_load_lds((const __attribute__((address_space(1))) void*)g,
                                   (__attribute__((address_space(3))) void*)l, 16, 0, 0);
}

// ---------------------------------------------------------------------------
// dtype detector: bf16-pair words have exponent-structured bits[14:7];
// fp32 words have uniform mantissa bits there. Writes flag: 1 = fp32 tensors.
// ---------------------------------------------------------------------------
__global__ __launch_bounds__(256) void detect_dtype(const uint32_t* __restrict__ q,
                                                    uint32_t* __restrict__ flag) {
  __shared__ int cnt;
  int t = threadIdx.x;
  if (t == 0) cnt = 0;
  __syncthreads();
  uint32_t w = q[t];
  int e = (int)((w >> 7) & 0xFF);
  int hit = (e >= 100 && e <= 141) ? 1 : 0;
  atomicAdd(&cnt, hit);
  __syncthreads();
  if (t == 0) *flag = (cnt >= 200) ? 0u : 1u;
}

// ---------------------------------------------------------------------------
// bf16 conversion pre-pass: convert (fp32 path) or copy (bf16 path) a tensor
// into a packed bf16 buffer. One-time cost unlocks global_load_lds staging
// in every GEMM.
// ---------------------------------------------------------------------------
__device__ __forceinline__ void cvt_body(const void* __restrict__ src,
                                         short* __restrict__ d, long n8, int f) {
  long i = (long)blockIdx.x * 256 + threadIdx.x;
  const long stride = (long)gridDim.x * 256;
  if (f) {
    const f32x4* s = (const f32x4*)src;
    for (; i < n8; i += stride) {
      f32x4 a = s[2 * i], b = s[2 * i + 1];
      bf16x8 r;
      r[0] = f2bf(a[0]); r[1] = f2bf(a[1]); r[2] = f2bf(a[2]); r[3] = f2bf(a[3]);
      r[4] = f2bf(b[0]); r[5] = f2bf(b[1]); r[6] = f2bf(b[2]); r[7] = f2bf(b[3]);
      *(bf16x8*)(d + i * 8) = r;
    }
  } else {
    const bf16x8* s = (const bf16x8*)src;
    for (; i < n8; i += stride) *(bf16x8*)(d + i * 8) = s[i];
  }
}

__global__ __launch_bounds__(256) void to_bf16_batch(
    const void* __restrict__ q, const void* __restrict__ k, const void* __restrict__ v,
    const void* __restrict__ wq, const void* __restrict__ wk, const void* __restrict__ wv,
    short* __restrict__ dst, const uint32_t* __restrict__ flag) {
  const void* src; long n8; long doff;
  switch (blockIdx.y) {
    case 0:  src = q;  n8 = 524288; doff = 0;        break;
    case 1:  src = k;  n8 = 524288; doff = 4194304;  break;
    case 2:  src = v;  n8 = 524288; doff = 8388608;  break;
    case 3:  src = wq; n8 = 131072; doff = 12582912; break;
    case 4:  src = wk; n8 = 131072; doff = 13631488; break;
    default: src = wv; n8 = 131072; doff = 14680064; break;
  }
  cvt_body(src, dst + doff, n8, (int)*flag);
}

__global__ __launch_bounds__(256) void to_bf16_one(const void* __restrict__ src,
                                                   short* __restrict__ dst, long n8,
                                                   const uint32_t* __restrict__ flag) {
  cvt_body(src, dst, n8, (int)*flag);
}

// ---------------------------------------------------------------------------
// NT GEMM (m97 structure): C[m,n] = sum_k A[m,k]*W[n,k], M=4096, N=K=1024,
// tile 128x128xBK64. Staging via global_load_lds_dwordx4 into LINEAR LDS
// [128][64] shorts; bank conflicts on ds_read_b128 avoided by pre-swizzling
// the GLOBAL source column chunk (c8 ^= r&7) and XOR-ing back on the read
// (m173/m201 pattern; swizzle stays within one 128B row -> no coalescing loss).
// MODE 0: dst=qh [b,h,s,dh] bf16, scaled by 0.125*log2(e)
// MODE 1: dst=kh [b,h,s,dh] bf16
// MODE 2: dst=vt [b,h,dh,s] bf16 (A/B roles swapped so D is transposed)
// MODE 3: dst=out row-major [m,n]; fp32 (dstF) when outf, else bf16 (dst)
// ---------------------------------------------------------------------------
template <int MODE>
__device__ __forceinline__ void gemm_body(short* sA, short* sW,
    const short* __restrict__ A, const short* __restrict__ W,
    short* __restrict__ dst, float* __restrict__ dstF, int outf) {
  const int tid = threadIdx.x;
  const int wave = tid >> 6, lane = tid & 63;
  const int quad = lane >> 4, l16 = lane & 15;
  const int m0 = blockIdx.x * 128, n0 = blockIdx.y * 128;
  const int wm = wave >> 1, wn = wave & 1;

  f32x4 acc[4][4] = {};

  for (int k0 = 0; k0 < 1024; k0 += 64) {
    // stage 128x64 A-tile and W-tile: 1024 16B chunks each, 4 per thread.
    // chunk c -> row r=c>>3, col chunk c8=c&7; source col pre-swizzled.
#pragma unroll
    for (int it = 0; it < 4; ++it) {
      int c = it * 256 + tid;
      int r = c >> 3, cs = (c & 7) ^ (r & 7);
      int ldsoff = (it * 256 + wave * 64) * 8;  // wave-uniform; lane*16B implicit
      gload16(A + (long)(m0 + r) * 1024 + k0 + cs * 8, sA + ldsoff);
      gload16(W + (long)(n0 + r) * 1024 + k0 + cs * 8, sW + ldsoff);
    }
    __syncthreads();  // implicit vmcnt(0): staged tiles visible
    const short* Pa = (MODE == 2) ? sW : sA;
    const short* Pb = (MODE == 2) ? sA : sW;
#pragma unroll
    for (int kk = 0; kk < 2; ++kk) {
      const int cx = ((kk * 4 + quad) ^ (l16 & 7)) * 8;  // un-swizzle on read
      bf16x8 af[4], bfr[4];
#pragma unroll
      for (int i = 0; i < 4; ++i)
        af[i] = *(const bf16x8*)(Pa + (wm * 64 + i * 16 + l16) * 64 + cx);
#pragma unroll
      for (int j = 0; j < 4; ++j)
        bfr[j] = *(const bf16x8*)(Pb + (wn * 64 + j * 16 + l16) * 64 + cx);
#pragma unroll
      for (int i = 0; i < 4; ++i)
#pragma unroll
        for (int j = 0; j < 4; ++j)
          acc[i][j] = __builtin_amdgcn_mfma_f32_16x16x32_bf16(af[i], bfr[j], acc[i][j], 0, 0, 0);
    }
    __syncthreads();  // all frag reads done before restage
  }

  // Epilogue. C/D layout: col = lane&15, row = quad*4 + reg (m89-verified).
#pragma unroll
  for (int i = 0; i < 4; ++i)
#pragma unroll
    for (int j = 0; j < 4; ++j)
#pragma unroll
      for (int r = 0; r < 4; ++r) {
        float vv = acc[i][j][r];
        if (MODE == 0) vv *= 0.18033688011112042f;  // 0.125 * log2(e)
        if (MODE == 2) {
          int n = n0 + wm * 64 + i * 16 + quad * 4 + r;  // W row = channel
          int m = m0 + wn * 64 + j * 16 + l16;           // A row = token
          int b = m >> 11, s = m & 2047, h = n >> 6, dh = n & 63;
          dst[((long)((b * 16 + h) * 64 + dh)) * 2048 + s] = f2bf(vv);
        } else {
          int m = m0 + wm * 64 + i * 16 + quad * 4 + r;
          int n = n0 + wn * 64 + j * 16 + l16;
          if (MODE == 3) {
            if (outf) dstF[(long)m * 1024 + n] = vv;
            else      dst[(long)m * 1024 + n] = f2bf(vv);
          } else {
            int b = m >> 11, s = m & 2047, h = n >> 6, dh = n & 63;
            dst[((long)(b * 16 + h) * 2048 + s) * 64 + dh] = f2bf(vv);
          }
        }
      }
}

__global__ __launch_bounds__(256) void qkv_kernel(
    const short* __restrict__ qb, const short* __restrict__ kb, const short* __restrict__ vb,
    const short* __restrict__ Wqb, const short* __restrict__ Wkb, const short* __restrict__ Wvb,
    short* __restrict__ qh, short* __restrict__ kh, short* __restrict__ vt) {
  __shared__ __align__(16) short sA[128 * 64];
  __shared__ __align__(16) short sW[128 * 64];
  if (blockIdx.z == 0)      gemm_body<0>(sA, sW, qb, Wqb, qh, nullptr, 0);
  else if (blockIdx.z == 1) gemm_body<1>(sA, sW, kb, Wkb, kh, nullptr, 0);
  else                      gemm_body<2>(sA, sW, vb, Wvb, vt, nullptr, 0);
}

__global__ __launch_bounds__(256) void oproj_kernel(
    const short* __restrict__ o, const short* __restrict__ Wob,
    const uint32_t* __restrict__ flag,
    short* __restrict__ outB, float* __restrict__ outF) {
  __shared__ __align__(16) short sA[128 * 64];
  __shared__ __align__(16) short sW[128 * 64];
  gemm_body<3>(sA, sW, o, Wob, outB, outF, (int)*flag);
}

// ---------------------------------------------------------------------------
// Pack attn_mask (S x S int32, 0/1) into bits: word q*64 + (k>>5), bit k&31.
// ---------------------------------------------------------------------------
__global__ __launch_bounds__(256) void pack_mask(const int* __restrict__ mask,
                                                 uint32_t* __restrict__ bits) {
  int gt = blockIdx.x * 256 + threadIdx.x;
  int wid = gt >> 6, lane = gt & 63;
  int nw = (gridDim.x * 256) >> 6;
  for (int g = wid; g < (S_ * S_) / 64; g += nw) {
    int v = mask[(long)g * 64 + lane];
    unsigned long long b = __ballot(v != 0);
    if (lane == 0) bits[2 * g] = (uint32_t)b;
    if (lane == 1) bits[2 * g + 1] = (uint32_t)(b >> 32);
  }
}

// ---------------------------------------------------------------------------
// Attention: per (bh, 128-q tile): two passes over 64-key tiles.
// K/V double-buffered, staged via global_load_lds issued ONE TILE AHEAD,
// exactly one __syncthreads per key tile (its implicit vmcnt(0) drains the
// prefetch after it has been covered by compute). P tile is per-wave LDS:
// block barriers around it replaced by wave-local lgkmcnt(0)+sched_barrier.
// Same source-pre-swizzle as the GEMM for conflict-free ds_read_b128.
// qh pre-scaled by 0.125*log2(e) -> softmax via exp2 directly.
// ---------------------------------------------------------------------------
__global__ __launch_bounds__(256) void attn_kernel(
    const short* __restrict__ qh, const short* __restrict__ kh,
    const short* __restrict__ vt, const uint32_t* __restrict__ mbits,
    const uint32_t* __restrict__ flag,
    short* __restrict__ attnB, float* __restrict__ attnF, short* __restrict__ o) {
  __shared__ __align__(16) short sK[2][64 * 64];
  __shared__ __align__(16) short sV[2][64 * 64];
  __shared__ __align__(16) short sP[4][32 * LP];  // per-wave P tile (padded)
  const int tid = threadIdx.x;
  const int wave = tid >> 6, lane = tid & 63;
  const int quad = lane >> 4, l16 = lane & 15;
  const int q0 = blockIdx.x * 128;
  const int bh = blockIdx.y;
  const int outf = (int)*flag;
  const short* Qb = qh + (long)bh * S_ * 64;
  const short* Kb = kh + (long)bh * S_ * 64;
  const short* Vb = vt + (long)bh * 64 * S_;
  short* attnBb = attnB + (long)bh * S_ * S_;
  float* attnFb = attnF + (long)bh * S_ * S_;
  short* sPw = sP[wave];
  const uint32_t cm0 = 1u << l16, cm1 = 1u << (l16 + 16);

  // async stage of one 64x64 bf16 tile (8KB = 512 chunks, 2 per thread)
  auto stageK = [&](int kt, int b) {
#pragma unroll
    for (int it = 0; it < 2; ++it) {
      int c = it * 256 + tid;
      int r = c >> 3, cs = (c & 7) ^ (r & 7);
      gload16(Kb + (long)(kt * 64 + r) * 64 + cs * 8, &sK[b][(it * 256 + wave * 64) * 8]);
    }
  };
  auto stageV = [&](int kt, int b) {
#pragma unroll
    for (int it = 0; it < 2; ++it) {
      int c = it * 256 + tid;
      int r = c >> 3, cs = (c & 7) ^ (r & 7);
      gload16(Vb + (long)r * S_ + kt * 64 + cs * 8, &sV[b][(it * 256 + wave * 64) * 8]);
    }
  };

  // Q fragments, loop-invariant, straight from global (16B/lane, aligned)
  bf16x8 qf[2][2];
#pragma unroll
  for (int i = 0; i < 2; ++i)
#pragma unroll
    for (int kk = 0; kk < 2; ++kk)
      qf[i][kk] = *(const bf16x8*)(Qb + (long)(q0 + wave * 32 + i * 16 + l16) * 64 + kk * 32 + quad * 8);

  float mrun[2][4], lrun[2][4];
#pragma unroll
  for (int i = 0; i < 2; ++i)
#pragma unroll
    for (int r = 0; r < 4; ++r) { mrun[i][r] = -3e38f; lrun[i][r] = 0.f; }

  // ---------------- pass A: row max + sum ----------------
  stageK(0, 0);
  __syncthreads();
  int buf = 0;
  for (int kt = 0; kt < NKT_; ++kt) {
    const int k0 = kt * 64;
    if (kt + 1 < NKT_) stageK(kt + 1, buf ^ 1);  // prefetch hides HBM/L2 latency
    f32x4 acc[2][4] = {};
#pragma unroll
    for (int kk = 0; kk < 2; ++kk) {
      const int cx = ((kk * 4 + quad) ^ (l16 & 7)) * 8;
      bf16x8 bfr[4];
#pragma unroll
      for (int j = 0; j < 4; ++j)
        bfr[j] = *(const bf16x8*)(&sK[buf][(j * 16 + l16) * 64 + cx]);
#pragma unroll
      for (int i = 0; i < 2; ++i)
#pragma unroll
        for (int j = 0; j < 4; ++j)
          acc[i][j] = __builtin_amdgcn_mfma_f32_16x16x32_bf16(qf[i][kk], bfr[j], acc[i][j], 0, 0, 0);
    }
#pragma unroll
    for (int i = 0; i < 2; ++i)
#pragma unroll
      for (int r = 0; r < 4; ++r) {
        int qrow = q0 + wave * 32 + i * 16 + quad * 4 + r;
        const uint32_t* wp = mbits + qrow * 64 + (k0 >> 5);
        uint32_t w0 = wp[0], w1 = wp[1];
        float s0 = (w0 & cm0) ? acc[i][0][r] : -1e30f;
        float s1 = (w0 & cm1) ? acc[i][1][r] : -1e30f;
        float s2 = (w1 & cm0) ? acc[i][2][r] : -1e30f;
        float s3 = (w1 & cm1) ? acc[i][3][r] : -1e30f;
        float mx = fmaxf(fmaxf(s0, s1), fmaxf(s2, s3));
        mx = fmaxf(mx, __shfl_xor(mx, 1));
        mx = fmaxf(mx, __shfl_xor(mx, 2));
        mx = fmaxf(mx, __shfl_xor(mx, 4));
        mx = fmaxf(mx, __shfl_xor(mx, 8));
        float mold = mrun[i][r];
        float mnew = fmaxf(mold, mx);
        float sum = exp2f(s0 - mnew) + exp2f(s1 - mnew) + exp2f(s2 - mnew) + exp2f(s3 - mnew);
        sum += __shfl_xor(sum, 1);
        sum += __shfl_xor(sum, 2);
        sum += __shfl_xor(sum, 4);
        sum += __shfl_xor(sum, 8);
        lrun[i][r] = lrun[i][r] * exp2f(mold - mnew) + sum;
        mrun[i][r] = mnew;
      }
    __syncthreads();  // single barrier: releases sK[buf] AND drains prefetch
    buf ^= 1;
  }

  float invl[2][4];
#pragma unroll
  for (int i = 0; i < 2; ++i)
#pragma unroll
    for (int r = 0; r < 4; ++r) invl[i][r] = 1.0f / lrun[i][r];

  f32x4 acco[2][4] = {};

  // ---------------- pass B: p, attn write, PV ----------------
  stageK(0, 0); stageV(0, 0);
  __syncthreads();
  buf = 0;
  for (int kt = 0; kt < NKT_; ++kt) {
    const int k0 = kt * 64;
    if (kt + 1 < NKT_) { stageK(kt + 1, buf ^ 1); stageV(kt + 1, buf ^ 1); }
    f32x4 acc[2][4] = {};
#pragma unroll
    for (int kk = 0; kk < 2; ++kk) {
      const int cx = ((kk * 4 + quad) ^ (l16 & 7)) * 8;
      bf16x8 bfr[4];
#pragma unroll
      for (int j = 0; j < 4; ++j)
        bfr[j] = *(const bf16x8*)(&sK[buf][(j * 16 + l16) * 64 + cx]);
#pragma unroll
      for (int i = 0; i < 2; ++i)
#pragma unroll
        for (int j = 0; j < 4; ++j)
          acc[i][j] = __builtin_amdgcn_mfma_f32_16x16x32_bf16(qf[i][kk], bfr[j], acc[i][j], 0, 0, 0);
    }
    // write normalized P into per-wave padded LDS tile (plain layout, row*LP+col)
#pragma unroll
    for (int i = 0; i < 2; ++i)
#pragma unroll
      for (int r = 0; r < 4; ++r) {
        int qrow = q0 + wave * 32 + i * 16 + quad * 4 + r;
        const uint32_t* wp = mbits + qrow * 64 + (k0 >> 5);
        uint32_t w0 = wp[0], w1 = wp[1];
        float mm = mrun[i][r], il = invl[i][r];
        float s0 = (w0 & cm0) ? acc[i][0][r] : -1e30f;
        float s1 = (w0 & cm1) ? acc[i][1][r] : -1e30f;
        float s2 = (w1 & cm0) ? acc[i][2][r] : -1e30f;
        float s3 = (w1 & cm1) ? acc[i][3][r] : -1e30f;
        int rowL = i * 16 + quad * 4 + r;
        short* rp = sPw + rowL * LP;
        rp[0  + l16] = f2bf(exp2f(s0 - mm) * il);
        rp[16 + l16] = f2bf(exp2f(s1 - mm) * il);
        rp[32 + l16] = f2bf(exp2f(s2 - mm) * il);
        rp[48 + l16] = f2bf(exp2f(s3 - mm) * il);
      }
    // P tile is per-wave: wave-local LDS drain is enough (no block barrier).
    // Rule #18: sched_barrier(0) after inline-asm waitcnt so nothing hoists.
    asm volatile("s_waitcnt lgkmcnt(0)" ::: "memory");
    __builtin_amdgcn_sched_barrier(0);
    // attn tile out FIRST so store-acks retire under the PV MFMAs.
#pragma unroll
    for (int it = 0; it < 4; ++it) {
      int cid = it * 64 + lane;
      int rowL = cid >> 3, kc = cid & 7;
      bf16x8 vals = *(const bf16x8*)(sPw + rowL * LP + kc * 8);
      long base = (long)(q0 + wave * 32 + rowL) * S_ + k0 + kc * 8;
      if (outf) {
        f32x4 lo, hi;
#pragma unroll
        for (int e = 0; e < 4; ++e) { lo[e] = bf2f(vals[e]); hi[e] = bf2f(vals[e + 4]); }
        *(f32x4*)(attnFb + base) = lo;
        *(f32x4*)(attnFb + base + 4) = hi;
      } else {
        *(bf16x8*)(attnBb + base) = vals;
      }
    }
    // PV: A = P (from own sPw), B = V^T rows from sV[buf]
    bf16x8 vf[2][4];
#pragma unroll
    for (int kk = 0; kk < 2; ++kk) {
      const int cx = ((kk * 4 + quad) ^ (l16 & 7)) * 8;
#pragma unroll
      for (int jd = 0; jd < 4; ++jd)
        vf[kk][jd] = *(const bf16x8*)(&sV[buf][(jd * 16 + l16) * 64 + cx]);
    }
#pragma unroll
    for (int kk = 0; kk < 2; ++kk)
#pragma unroll
      for (int i = 0; i < 2; ++i) {
        bf16x8 pf = *(const bf16x8*)(sPw + (i * 16 + l16) * LP + (kk * 4 + quad) * 8);
#pragma unroll
        for (int jd = 0; jd < 4; ++jd)
          acco[i][jd] = __builtin_amdgcn_mfma_f32_16x16x32_bf16(pf, vf[kk][jd], acco[i][jd], 0, 0, 0);
      }
    __syncthreads();  // single barrier per tile: releases sK/sV[buf], drains prefetch+stores
    buf ^= 1;
  }

  // o epilogue: [b, s, h*64+dh], internal bf16
  const int b = bh >> 4, h = bh & 15;
#pragma unroll
  for (int i = 0; i < 2; ++i)
#pragma unroll
    for (int jd = 0; jd < 4; ++jd)
#pragma unroll
      for (int r = 0; r < 4; ++r) {
        int qrow = q0 + wave * 32 + i * 16 + quad * 4 + r;
        int dh = jd * 16 + l16;
        o[(long)(b * S_ + qrow) * 1024 + h * 64 + dh] = f2bf(acco[i][jd][r]);
      }
}

extern "C" void kernel_launch(void* const* d_in, const int* in_sizes, int n_in,
                              void* d_out, int out_size, void* d_ws, size_t ws_size,
                              hipStream_t stream) {
  (void)in_sizes; (void)n_in; (void)out_size; (void)ws_size;
  const void* q  = d_in[0];
  const void* k  = d_in[1];
  const void* v  = d_in[2];
  const int* mask = (const int*)d_in[3];
  const void* Wq = d_in[4];
  const void* Wk = d_in[5];
  const void* Wv = d_in[6];
  const void* Wo = d_in[7];

  // d_out = out [2,2048,1024] then attn [2,16,2048,2048], dtype per flag
  short* outB  = (short*)d_out;
  short* attnB = outB + (long)4194304;
  float* outF  = (float*)d_out;
  float* attnF = outF + (long)4194304;

  short* qh = (short*)d_ws;            // [2,16,2048,64] bf16, pre-scaled
  short* kh = qh + (long)4194304;      // [2,16,2048,64] bf16
  short* vt = kh + (long)4194304;      // [2,16,64,2048] bf16
  short* o  = vt + (long)4194304;      // [2,2048,1024] bf16
  uint32_t* mbits = (uint32_t*)(o + (long)4194304);  // [2048][64] words
  uint32_t* flag  = mbits + 131072;    // 1 = fp32 tensors

  // bf16 scratch parked inside the attn region of d_out (free until
  // attn_kernel runs, which then overwrites it; offset 20MB is inside the
  // attn region for BOTH fp32 and bf16 output modes, end 50MB << buffer).
  short* qb  = (short*)((char*)d_out + (20l << 20));
  short* kb  = qb  + (long)4194304;
  short* vb  = kb  + (long)4194304;
  short* wqb = vb  + (long)4194304;
  short* wkb = wqb + (long)1048576;
  short* wvb = wkb + (long)1048576;
  short* wob = qh;  // qh is dead after attn_kernel; reuse for Wo bf16

  detect_dtype<<<dim3(1), dim3(256), 0, stream>>>((const uint32_t*)q, flag);
  pack_mask<<<dim3(256), dim3(256), 0, stream>>>(mask, mbits);
  to_bf16_batch<<<dim3(512, 6), dim3(256), 0, stream>>>(q, k, v, Wq, Wk, Wv, qb, flag);
  qkv_kernel<<<dim3(32, 8, 3), dim3(256), 0, stream>>>(qb, kb, vb, wqb, wkb, wvb, qh, kh, vt);
  attn_kernel<<<dim3(16, 32), dim3(256), 0, stream>>>(qh, kh, vt, mbits, flag, attnB, attnF, o);
  to_bf16_one<<<dim3(512), dim3(256), 0, stream>>>(Wo, wob, 131072, flag);
  oproj_kernel<<<dim3(32, 8), dim3(256), 0, stream>>>(o, wob, flag, outB, outF);
}

// Round 3
// 859.511 us; speedup vs baseline: 1.1604x; 1.0354x over previous
//
#include <hip/hip_runtime.h>
#include <stdint.h>

// Problem constants: B=2, S=2048, D=1024, H=16, DH=64
#define S_ 2048
#define NKT_ 32   // S_/64 key tiles (pass B)
#define NKTA_ 16  // S_/128 key tiles (pass A)
#define LP 72     // padded LDS row stride in shorts for the P tile only

typedef short bf16x8 __attribute__((ext_vector_type(8)));
typedef float f32x4 __attribute__((ext_vector_type(4)));

// fp32 -> bf16 round-to-nearest-even
__device__ __forceinline__ short f2bf(float x) {
  union { float f; uint32_t u; } v; v.f = x;
  uint32_t r = v.u + 0x7fffu + ((v.u >> 16) & 1u);
  return (short)(r >> 16);
}
// bf16 bits -> fp32
__device__ __forceinline__ float bf2f(short s) {
  union { uint32_t u; float f; } v; v.u = ((uint32_t)(uint16_t)s) << 16;
  return v.f;
}

// async global->LDS, 16B per lane. LDS dest is wave-uniform base + lane*16
// (hardware semantics); global src is per-lane.
__device__ __forceinline__ void gload16(const void* g, void* l) {
  __builtin_amdgcn_global_load_lds((const __attribute__((address_space(1))) void*)g,
                                   (__attribute__((address_space(3))) void*)l, 16, 0, 0);
}

// ---------------------------------------------------------------------------
// dtype detector: bf16-pair words have exponent-structured bits[14:7];
// fp32 words have uniform mantissa bits there. Writes flag: 1 = fp32 tensors.
// ---------------------------------------------------------------------------
__global__ __launch_bounds__(256) void detect_dtype(const uint32_t* __restrict__ q,
                                                    uint32_t* __restrict__ flag) {
  __shared__ int cnt;
  int t = threadIdx.x;
  if (t == 0) cnt = 0;
  __syncthreads();
  uint32_t w = q[t];
  int e = (int)((w >> 7) & 0xFF);
  int hit = (e >= 100 && e <= 141) ? 1 : 0;
  atomicAdd(&cnt, hit);
  __syncthreads();
  if (t == 0) *flag = (cnt >= 200) ? 0u : 1u;
}

// ---------------------------------------------------------------------------
// bf16 conversion pre-pass: convert (fp32 path) or copy (bf16 path) a tensor
// into a packed bf16 buffer. One-time cost unlocks global_load_lds staging
// in every GEMM.
// ---------------------------------------------------------------------------
__device__ __forceinline__ void cvt_body(const void* __restrict__ src,
                                         short* __restrict__ d, long n8, int f) {
  long i = (long)blockIdx.x * 256 + threadIdx.x;
  const long stride = (long)gridDim.x * 256;
  if (f) {
    const f32x4* s = (const f32x4*)src;
    for (; i < n8; i += stride) {
      f32x4 a = s[2 * i], b = s[2 * i + 1];
      bf16x8 r;
      r[0] = f2bf(a[0]); r[1] = f2bf(a[1]); r[2] = f2bf(a[2]); r[3] = f2bf(a[3]);
      r[4] = f2bf(b[0]); r[5] = f2bf(b[1]); r[6] = f2bf(b[2]); r[7] = f2bf(b[3]);
      *(bf16x8*)(d + i * 8) = r;
    }
  } else {
    const bf16x8* s = (const bf16x8*)src;
    for (; i < n8; i += stride) *(bf16x8*)(d + i * 8) = s[i];
  }
}

__global__ __launch_bounds__(256) void to_bf16_batch(
    const void* __restrict__ q, const void* __restrict__ k, const void* __restrict__ v,
    const void* __restrict__ wq, const void* __restrict__ wk, const void* __restrict__ wv,
    short* __restrict__ dst, const uint32_t* __restrict__ flag) {
  const void* src; long n8; long doff;
  switch (blockIdx.y) {
    case 0:  src = q;  n8 = 524288; doff = 0;        break;
    case 1:  src = k;  n8 = 524288; doff = 4194304;  break;
    case 2:  src = v;  n8 = 524288; doff = 8388608;  break;
    case 3:  src = wq; n8 = 131072; doff = 12582912; break;
    case 4:  src = wk; n8 = 131072; doff = 13631488; break;
    default: src = wv; n8 = 131072; doff = 14680064; break;
  }
  cvt_body(src, dst + doff, n8, (int)*flag);
}

__global__ __launch_bounds__(256) void to_bf16_one(const void* __restrict__ src,
                                                   short* __restrict__ dst, long n8,
                                                   const uint32_t* __restrict__ flag) {
  cvt_body(src, dst, n8, (int)*flag);
}

// ---------------------------------------------------------------------------
// NT GEMM (m97 structure): C[m,n] = sum_k A[m,k]*W[n,k], M=4096, N=K=1024,
// tile 128x128xBK64. Staging via global_load_lds_dwordx4 into LINEAR LDS
// [128][64] shorts; bank conflicts on ds_read_b128 avoided by pre-swizzling
// the GLOBAL source column chunk (c8 ^= r&7) and XOR-ing back on the read.
// MODE 0: dst=qh [b,h,s,dh] bf16, scaled by 0.125*log2(e)
// MODE 1: dst=kh [b,h,s,dh] bf16
// MODE 2: dst=vt [b,h,dh,s] bf16 (A/B roles swapped so D is transposed)
// MODE 3: dst=out row-major [m,n]; fp32 (dstF) when outf, else bf16 (dst)
// ---------------------------------------------------------------------------
template <int MODE>
__device__ __forceinline__ void gemm_body(short* sA, short* sW,
    const short* __restrict__ A, const short* __restrict__ W,
    short* __restrict__ dst, float* __restrict__ dstF, int outf) {
  const int tid = threadIdx.x;
  const int wave = tid >> 6, lane = tid & 63;
  const int quad = lane >> 4, l16 = lane & 15;
  const int m0 = blockIdx.x * 128, n0 = blockIdx.y * 128;
  const int wm = wave >> 1, wn = wave & 1;

  f32x4 acc[4][4] = {};

  for (int k0 = 0; k0 < 1024; k0 += 64) {
#pragma unroll
    for (int it = 0; it < 4; ++it) {
      int c = it * 256 + tid;
      int r = c >> 3, cs = (c & 7) ^ (r & 7);
      int ldsoff = (it * 256 + wave * 64) * 8;  // wave-uniform; lane*16B implicit
      gload16(A + (long)(m0 + r) * 1024 + k0 + cs * 8, sA + ldsoff);
      gload16(W + (long)(n0 + r) * 1024 + k0 + cs * 8, sW + ldsoff);
    }
    __syncthreads();  // implicit vmcnt(0): staged tiles visible
    const short* Pa = (MODE == 2) ? sW : sA;
    const short* Pb = (MODE == 2) ? sA : sW;
#pragma unroll
    for (int kk = 0; kk < 2; ++kk) {
      const int cx = ((kk * 4 + quad) ^ (l16 & 7)) * 8;  // un-swizzle on read
      bf16x8 af[4], bfr[4];
#pragma unroll
      for (int i = 0; i < 4; ++i)
        af[i] = *(const bf16x8*)(Pa + (wm * 64 + i * 16 + l16) * 64 + cx);
#pragma unroll
      for (int j = 0; j < 4; ++j)
        bfr[j] = *(const bf16x8*)(Pb + (wn * 64 + j * 16 + l16) * 64 + cx);
#pragma unroll
      for (int i = 0; i < 4; ++i)
#pragma unroll
        for (int j = 0; j < 4; ++j)
          acc[i][j] = __builtin_amdgcn_mfma_f32_16x16x32_bf16(af[i], bfr[j], acc[i][j], 0, 0, 0);
    }
    __syncthreads();  // all frag reads done before restage
  }

  // Epilogue. C/D layout: col = lane&15, row = quad*4 + reg (m89-verified).
#pragma unroll
  for (int i = 0; i < 4; ++i)
#pragma unroll
    for (int j = 0; j < 4; ++j)
#pragma unroll
      for (int r = 0; r < 4; ++r) {
        float vv = acc[i][j][r];
        if (MODE == 0) vv *= 0.18033688011112042f;  // 0.125 * log2(e)
        if (MODE == 2) {
          int n = n0 + wm * 64 + i * 16 + quad * 4 + r;  // W row = channel
          int m = m0 + wn * 64 + j * 16 + l16;           // A row = token
          int b = m >> 11, s = m & 2047, h = n >> 6, dh = n & 63;
          dst[((long)((b * 16 + h) * 64 + dh)) * 2048 + s] = f2bf(vv);
        } else {
          int m = m0 + wm * 64 + i * 16 + quad * 4 + r;
          int n = n0 + wn * 64 + j * 16 + l16;
          if (MODE == 3) {
            if (outf) dstF[(long)m * 1024 + n] = vv;
            else      dst[(long)m * 1024 + n] = f2bf(vv);
          } else {
            int b = m >> 11, s = m & 2047, h = n >> 6, dh = n & 63;
            dst[((long)(b * 16 + h) * 2048 + s) * 64 + dh] = f2bf(vv);
          }
        }
      }
}

__global__ __launch_bounds__(256) void qkv_kernel(
    const short* __restrict__ qb, const short* __restrict__ kb, const short* __restrict__ vb,
    const short* __restrict__ Wqb, const short* __restrict__ Wkb, const short* __restrict__ Wvb,
    short* __restrict__ qh, short* __restrict__ kh, short* __restrict__ vt) {
  __shared__ __align__(16) short sA[128 * 64];
  __shared__ __align__(16) short sW[128 * 64];
  if (blockIdx.z == 0)      gemm_body<0>(sA, sW, qb, Wqb, qh, nullptr, 0);
  else if (blockIdx.z == 1) gemm_body<1>(sA, sW, kb, Wkb, kh, nullptr, 0);
  else                      gemm_body<2>(sA, sW, vb, Wvb, vt, nullptr, 0);
}

__global__ __launch_bounds__(256) void oproj_kernel(
    const short* __restrict__ o, const short* __restrict__ Wob,
    const uint32_t* __restrict__ flag,
    short* __restrict__ outB, float* __restrict__ outF) {
  __shared__ __align__(16) short sA[128 * 64];
  __shared__ __align__(16) short sW[128 * 64];
  gemm_body<3>(sA, sW, o, Wob, outB, outF, (int)*flag);
}

// ---------------------------------------------------------------------------
// Pack attn_mask (S x S int32, 0/1) into bits: word q*64 + (k>>5), bit k&31.
// ---------------------------------------------------------------------------
__global__ __launch_bounds__(256) void pack_mask(const int* __restrict__ mask,
                                                 uint32_t* __restrict__ bits) {
  int gt = blockIdx.x * 256 + threadIdx.x;
  int wid = gt >> 6, lane = gt & 63;
  int nw = (gridDim.x * 256) >> 6;
  for (int g = wid; g < (S_ * S_) / 64; g += nw) {
    int v = mask[(long)g * 64 + lane];
    unsigned long long b = __ballot(v != 0);
    if (lane == 0) bits[2 * g] = (uint32_t)b;
    if (lane == 1) bits[2 * g + 1] = (uint32_t)(b >> 32);
  }
}

// ---------------------------------------------------------------------------
// Attention, per (bh, 128-q tile). XCD-aware remap: all 16 q-tiles of a head
// run on one XCD so each head's K/V is fetched into exactly one L2 (T1).
// Pass A: KVBLK=128 (double-buffered in sK+sV space), computes row max+sum.
//   Halves barriers/shfl-chains vs KVBLK=64; mask via one dwordx4 per combo.
// Pass B: KVBLK=64, K/V double-buffered, prefetched one tile ahead, single
//   barrier per tile; P per-wave in LDS (wave-local lgkmcnt ordering).
// s_setprio(1) around MFMA clusters (T5, attn-positive m191).
// qh pre-scaled by 0.125*log2(e) -> softmax via exp2 directly.
// ---------------------------------------------------------------------------
__global__ __launch_bounds__(256) void attn_kernel(
    const short* __restrict__ qh, const short* __restrict__ kh,
    const short* __restrict__ vt, const uint32_t* __restrict__ mbits,
    const uint32_t* __restrict__ flag,
    short* __restrict__ attnB, float* __restrict__ attnF, short* __restrict__ o) {
  __shared__ __align__(16) short sK[2][64 * 64];
  __shared__ __align__(16) short sV[2][64 * 64];
  __shared__ __align__(16) short sP[4][32 * LP];  // per-wave P tile (padded)
  const int tid = threadIdx.x;
  const int wave = tid >> 6, lane = tid & 63;
  const int quad = lane >> 4, l16 = lane & 15;
  // XCD-aware remap (bijective; 512 = 8 XCD x 4 bh x 16 q-tiles)
  const int bidf = blockIdx.y * 16 + blockIdx.x;
  const int bh = (bidf & 7) * 4 + ((bidf >> 3) >> 4);
  const int q0 = ((bidf >> 3) & 15) * 128;
  const int outf = (int)*flag;
  const short* Qb = qh + (long)bh * S_ * 64;
  const short* Kb = kh + (long)bh * S_ * 64;
  const short* Vb = vt + (long)bh * 64 * S_;
  short* attnBb = attnB + (long)bh * S_ * S_;
  float* attnFb = attnF + (long)bh * S_ * S_;
  short* sPw = sP[wave];
  const uint32_t cm0 = 1u << l16, cm1 = 1u << (l16 + 16);

  // ----- staging lambdas -----
  // pass A: 128x64 K tile (16KB) -> bufA(0)=sK storage, bufA(1)=sV storage
  auto bufA = [&](int b) -> short* { return b ? &sV[0][0] : &sK[0][0]; };
  auto stageA = [&](int kt, int b) {
    short* dstp = bufA(b);
#pragma unroll
    for (int it = 0; it < 4; ++it) {
      int c = it * 256 + tid;
      int r = c >> 3, cs = (c & 7) ^ (r & 7);
      gload16(Kb + (long)(kt * 128 + r) * 64 + cs * 8, dstp + (it * 256 + wave * 64) * 8);
    }
  };
  // pass B: 64x64 tiles (8KB each)
  auto stageK = [&](int kt, int b) {
#pragma unroll
    for (int it = 0; it < 2; ++it) {
      int c = it * 256 + tid;
      int r = c >> 3, cs = (c & 7) ^ (r & 7);
      gload16(Kb + (long)(kt * 64 + r) * 64 + cs * 8, &sK[b][(it * 256 + wave * 64) * 8]);
    }
  };
  auto stageV = [&](int kt, int b) {
#pragma unroll
    for (int it = 0; it < 2; ++it) {
      int c = it * 256 + tid;
      int r = c >> 3, cs = (c & 7) ^ (r & 7);
      gload16(Vb + (long)r * S_ + kt * 64 + cs * 8, &sV[b][(it * 256 + wave * 64) * 8]);
    }
  };

  // Q fragments, loop-invariant, straight from global (16B/lane, aligned)
  bf16x8 qf[2][2];
#pragma unroll
  for (int i = 0; i < 2; ++i)
#pragma unroll
    for (int kk = 0; kk < 2; ++kk)
      qf[i][kk] = *(const bf16x8*)(Qb + (long)(q0 + wave * 32 + i * 16 + l16) * 64 + kk * 32 + quad * 8);

  float mrun[2][4], lrun[2][4];
#pragma unroll
  for (int i = 0; i < 2; ++i)
#pragma unroll
    for (int r = 0; r < 4; ++r) { mrun[i][r] = -3e38f; lrun[i][r] = 0.f; }

  // ---------------- pass A: row max + sum (KVBLK=128) ----------------
  stageA(0, 0);
  __syncthreads();
  int buf = 0;
  for (int kt = 0; kt < NKTA_; ++kt) {
    if (kt + 1 < NKTA_) stageA(kt + 1, buf ^ 1);  // prefetch hides HBM/L2 latency
    const short* Kt = bufA(buf);
    f32x4 acc[2][8] = {};
#pragma unroll
    for (int kk = 0; kk < 2; ++kk) {
      const int cx = ((kk * 4 + quad) ^ (l16 & 7)) * 8;
      bf16x8 bfr[8];
#pragma unroll
      for (int j = 0; j < 8; ++j)
        bfr[j] = *(const bf16x8*)(Kt + (j * 16 + l16) * 64 + cx);
      __builtin_amdgcn_s_setprio(1);
#pragma unroll
      for (int i = 0; i < 2; ++i)
#pragma unroll
        for (int j = 0; j < 8; ++j)
          acc[i][j] = __builtin_amdgcn_mfma_f32_16x16x32_bf16(qf[i][kk], bfr[j], acc[i][j], 0, 0, 0);
      __builtin_amdgcn_s_setprio(0);
    }
#pragma unroll
    for (int i = 0; i < 2; ++i)
#pragma unroll
      for (int r = 0; r < 4; ++r) {
        int qrow = q0 + wave * 32 + i * 16 + quad * 4 + r;
        uint4 w = *(const uint4*)(mbits + qrow * 64 + kt * 4);
        float s0 = (w.x & cm0) ? acc[i][0][r] : -1e30f;
        float s1 = (w.x & cm1) ? acc[i][1][r] : -1e30f;
        float s2 = (w.y & cm0) ? acc[i][2][r] : -1e30f;
        float s3 = (w.y & cm1) ? acc[i][3][r] : -1e30f;
        float s4 = (w.z & cm0) ? acc[i][4][r] : -1e30f;
        float s5 = (w.z & cm1) ? acc[i][5][r] : -1e30f;
        float s6 = (w.w & cm0) ? acc[i][6][r] : -1e30f;
        float s7 = (w.w & cm1) ? acc[i][7][r] : -1e30f;
        float mx = fmaxf(fmaxf(fmaxf(s0, s1), fmaxf(s2, s3)),
                         fmaxf(fmaxf(s4, s5), fmaxf(s6, s7)));
        mx = fmaxf(mx, __shfl_xor(mx, 1));
        mx = fmaxf(mx, __shfl_xor(mx, 2));
        mx = fmaxf(mx, __shfl_xor(mx, 4));
        mx = fmaxf(mx, __shfl_xor(mx, 8));
        float mold = mrun[i][r];
        float mnew = fmaxf(mold, mx);
        float sum = exp2f(s0 - mnew) + exp2f(s1 - mnew) + exp2f(s2 - mnew) + exp2f(s3 - mnew)
                  + exp2f(s4 - mnew) + exp2f(s5 - mnew) + exp2f(s6 - mnew) + exp2f(s7 - mnew);
        sum += __shfl_xor(sum, 1);
        sum += __shfl_xor(sum, 2);
        sum += __shfl_xor(sum, 4);
        sum += __shfl_xor(sum, 8);
        lrun[i][r] = lrun[i][r] * exp2f(mold - mnew) + sum;
        mrun[i][r] = mnew;
      }
    __syncthreads();  // releases bufA(buf) AND drains prefetch
    buf ^= 1;
  }

  float invl[2][4];
#pragma unroll
  for (int i = 0; i < 2; ++i)
#pragma unroll
    for (int r = 0; r < 4; ++r) invl[i][r] = 1.0f / lrun[i][r];

  f32x4 acco[2][4] = {};

  // ---------------- pass B: p, attn write, PV (KVBLK=64) ----------------
  stageK(0, 0); stageV(0, 0);
  __syncthreads();
  buf = 0;
  for (int kt = 0; kt < NKT_; ++kt) {
    const int k0 = kt * 64;
    if (kt + 1 < NKT_) { stageK(kt + 1, buf ^ 1); stageV(kt + 1, buf ^ 1); }
    f32x4 acc[2][4] = {};
#pragma unroll
    for (int kk = 0; kk < 2; ++kk) {
      const int cx = ((kk * 4 + quad) ^ (l16 & 7)) * 8;
      bf16x8 bfr[4];
#pragma unroll
      for (int j = 0; j < 4; ++j)
        bfr[j] = *(const bf16x8*)(&sK[buf][(j * 16 + l16) * 64 + cx]);
      __builtin_amdgcn_s_setprio(1);
#pragma unroll
      for (int i = 0; i < 2; ++i)
#pragma unroll
        for (int j = 0; j < 4; ++j)
          acc[i][j] = __builtin_amdgcn_mfma_f32_16x16x32_bf16(qf[i][kk], bfr[j], acc[i][j], 0, 0, 0);
      __builtin_amdgcn_s_setprio(0);
    }
    // write normalized P into per-wave padded LDS tile (plain layout, row*LP+col)
#pragma unroll
    for (int i = 0; i < 2; ++i)
#pragma unroll
      for (int r = 0; r < 4; ++r) {
        int qrow = q0 + wave * 32 + i * 16 + quad * 4 + r;
        const uint32_t* wp = mbits + qrow * 64 + (k0 >> 5);
        uint32_t w0 = wp[0], w1 = wp[1];
        float mm = mrun[i][r], il = invl[i][r];
        float s0 = (w0 & cm0) ? acc[i][0][r] : -1e30f;
        float s1 = (w0 & cm1) ? acc[i][1][r] : -1e30f;
        float s2 = (w1 & cm0) ? acc[i][2][r] : -1e30f;
        float s3 = (w1 & cm1) ? acc[i][3][r] : -1e30f;
        int rowL = i * 16 + quad * 4 + r;
        short* rp = sPw + rowL * LP;
        rp[0  + l16] = f2bf(exp2f(s0 - mm) * il);
        rp[16 + l16] = f2bf(exp2f(s1 - mm) * il);
        rp[32 + l16] = f2bf(exp2f(s2 - mm) * il);
        rp[48 + l16] = f2bf(exp2f(s3 - mm) * il);
      }
    // P tile is per-wave: wave-local LDS drain is enough (no block barrier).
    // Rule #18: sched_barrier(0) after inline-asm waitcnt so nothing hoists.
    asm volatile("s_waitcnt lgkmcnt(0)" ::: "memory");
    __builtin_amdgcn_sched_barrier(0);
    // attn tile out FIRST so store-acks retire under the PV MFMAs.
#pragma unroll
    for (int it = 0; it < 4; ++it) {
      int cid = it * 64 + lane;
      int rowL = cid >> 3, kc = cid & 7;
      bf16x8 vals = *(const bf16x8*)(sPw + rowL * LP + kc * 8);
      long base = (long)(q0 + wave * 32 + rowL) * S_ + k0 + kc * 8;
      if (outf) {
        f32x4 lo, hi;
#pragma unroll
        for (int e = 0; e < 4; ++e) { lo[e] = bf2f(vals[e]); hi[e] = bf2f(vals[e + 4]); }
        *(f32x4*)(attnFb + base) = lo;
        *(f32x4*)(attnFb + base + 4) = hi;
      } else {
        *(bf16x8*)(attnBb + base) = vals;
      }
    }
    // PV: A = P (from own sPw), B = V^T rows from sV[buf]
    bf16x8 vf[2][4];
#pragma unroll
    for (int kk = 0; kk < 2; ++kk) {
      const int cx = ((kk * 4 + quad) ^ (l16 & 7)) * 8;
#pragma unroll
      for (int jd = 0; jd < 4; ++jd)
        vf[kk][jd] = *(const bf16x8*)(&sV[buf][(jd * 16 + l16) * 64 + cx]);
    }
    __builtin_amdgcn_s_setprio(1);
#pragma unroll
    for (int kk = 0; kk < 2; ++kk)
#pragma unroll
      for (int i = 0; i < 2; ++i) {
        bf16x8 pf = *(const bf16x8*)(sPw + (i * 16 + l16) * LP + (kk * 4 + quad) * 8);
#pragma unroll
        for (int jd = 0; jd < 4; ++jd)
          acco[i][jd] = __builtin_amdgcn_mfma_f32_16x16x32_bf16(pf, vf[kk][jd], acco[i][jd], 0, 0, 0);
      }
    __builtin_amdgcn_s_setprio(0);
    __syncthreads();  // single barrier per tile: releases sK/sV[buf], drains prefetch+stores
    buf ^= 1;
  }

  // o epilogue: [b, s, h*64+dh], internal bf16
  const int b = bh >> 4, h = bh & 15;
#pragma unroll
  for (int i = 0; i < 2; ++i)
#pragma unroll
    for (int jd = 0; jd < 4; ++jd)
#pragma unroll
      for (int r = 0; r < 4; ++r) {
        int qrow = q0 + wave * 32 + i * 16 + quad * 4 + r;
        int dh = jd * 16 + l16;
        o[(long)(b * S_ + qrow) * 1024 + h * 64 + dh] = f2bf(acco[i][jd][r]);
      }
}

extern "C" void kernel_launch(void* const* d_in, const int* in_sizes, int n_in,
                              void* d_out, int out_size, void* d_ws, size_t ws_size,
                              hipStream_t stream) {
  (void)in_sizes; (void)n_in; (void)out_size; (void)ws_size;
  const void* q  = d_in[0];
  const void* k  = d_in[1];
  const void* v  = d_in[2];
  const int* mask = (const int*)d_in[3];
  const void* Wq = d_in[4];
  const void* Wk = d_in[5];
  const void* Wv = d_in[6];
  const void* Wo = d_in[7];

  // d_out = out [2,2048,1024] then attn [2,16,2048,2048], dtype per flag
  short* outB  = (short*)d_out;
  short* attnB = outB + (long)4194304;
  float* outF  = (float*)d_out;
  float* attnF = outF + (long)4194304;

  short* qh = (short*)d_ws;            // [2,16,2048,64] bf16, pre-scaled
  short* kh = qh + (long)4194304;      // [2,16,2048,64] bf16
  short* vt = kh + (long)4194304;      // [2,16,64,2048] bf16
  short* o  = vt + (long)4194304;      // [2,2048,1024] bf16
  uint32_t* mbits = (uint32_t*)(o + (long)4194304);  // [2048][64] words
  uint32_t* flag  = mbits + 131072;    // 1 = fp32 tensors

  // bf16 scratch parked inside the attn region of d_out (free until
  // attn_kernel runs, which then overwrites it; offset 20MB is inside the
  // attn region for BOTH fp32 and bf16 output modes, end 50MB << buffer).
  short* qb  = (short*)((char*)d_out + (20l << 20));
  short* kb  = qb  + (long)4194304;
  short* vb  = kb  + (long)4194304;
  short* wqb = vb  + (long)4194304;
  short* wkb = wqb + (long)1048576;
  short* wvb = wkb + (long)1048576;
  short* wob = qh;  // qh is dead after attn_kernel; reuse for Wo bf16

  detect_dtype<<<dim3(1), dim3(256), 0, stream>>>((const uint32_t*)q, flag);
  pack_mask<<<dim3(256), dim3(256), 0, stream>>>(mask, mbits);
  to_bf16_batch<<<dim3(512, 6), dim3(256), 0, stream>>>(q, k, v, Wq, Wk, Wv, qb, flag);
  qkv_kernel<<<dim3(32, 8, 3), dim3(256), 0, stream>>>(qb, kb, vb, wqb, wkb, wvb, qh, kh, vt);
  attn_kernel<<<dim3(16, 32), dim3(256), 0, stream>>>(qh, kh, vt, mbits, flag, attnB, attnF, o);
  to_bf16_one<<<dim3(512), dim3(256), 0, stream>>>(Wo, wob, 131072, flag);
  oproj_kernel<<<dim3(32, 8), dim3(256), 0, stream>>>(o, wob, flag, outB, outF);
}